// Round 6
// baseline (37223.337 us; speedup 1.0000x reference)
//
#include <hip/hip_runtime.h>
#include <hip/hip_cooperative_groups.h>

namespace cg = cooperative_groups;

#define BB 64
#define SS 196
#define EE 512
#define DD 2048
#define MM 25
#define HNN 32
#define NHH 8
#define TT 50
#define NSS 512
#define OUTN 1000
#define HDD 64
#define KSYN 2560
#define NSYN 4096

#define CERT_OFF 3200000
#define SYNC_OFF 3206400

__device__ __forceinline__ float sigm(float x){ return 1.f / (1.f + expf(-x)); }
__device__ __forceinline__ int rfl(int x){ return __builtin_amdgcn_readfirstlane(x); }

// ---------------- f32 GEMM (precompute): C = A(M,K) @ W(K,N) + bias ----------------
// LAYOUT 0: row-major. 1: vh permute ((b*8+h)*196+s)*64+d. 2: transposed C[col][row].
// 3: khT permute ((b*8+h)*64+d)*196+s.  ro = global row offset for layouts 1/3.
template<int LAYOUT>
__global__ __launch_bounds__(256) void sgemm(
    const float* __restrict__ Ag, const float* __restrict__ Wg,
    const float* __restrict__ bias, float* __restrict__ Cg,
    int Mg, int Ng, int Kg, int ro)
{
  __shared__ float As[16][68];
  __shared__ float Bs[16][68];
  int t = threadIdx.x;
  int bm = blockIdx.x * 64, bn = blockIdx.y * 64;
  int ty = t >> 4, tx = t & 15;
  int atm = t >> 2, atk = (t & 3) * 4;
  int bkk = t >> 4, bnn = (t & 15) * 4;
  float c[4][4] = {};
  for (int k0 = 0; k0 < Kg; k0 += 16){
    float4 av = *reinterpret_cast<const float4*>(Ag + (size_t)(bm + atm) * Kg + k0 + atk);
    As[atk][atm] = av.x; As[atk + 1][atm] = av.y;
    As[atk + 2][atm] = av.z; As[atk + 3][atm] = av.w;
    float4 bv = *reinterpret_cast<const float4*>(Wg + (size_t)(k0 + bkk) * Ng + bn + bnn);
    *reinterpret_cast<float4*>(&Bs[bkk][bnn]) = bv;
    __syncthreads();
    #pragma unroll
    for (int k = 0; k < 16; k++){
      float4 a = *reinterpret_cast<const float4*>(&As[k][ty * 4]);
      float4 b = *reinterpret_cast<const float4*>(&Bs[k][tx * 4]);
      c[0][0] += a.x * b.x; c[0][1] += a.x * b.y; c[0][2] += a.x * b.z; c[0][3] += a.x * b.w;
      c[1][0] += a.y * b.x; c[1][1] += a.y * b.y; c[1][2] += a.y * b.z; c[1][3] += a.y * b.w;
      c[2][0] += a.z * b.x; c[2][1] += a.z * b.y; c[2][2] += a.z * b.z; c[2][3] += a.z * b.w;
      c[3][0] += a.w * b.x; c[3][1] += a.w * b.y; c[3][2] += a.w * b.z; c[3][3] += a.w * b.w;
    }
    __syncthreads();
  }
  #pragma unroll
  for (int j = 0; j < 4; j++){
    int col = bn + tx * 4 + j;
    float bvv = bias ? bias[col] : 0.f;
    #pragma unroll
    for (int i = 0; i < 4; i++){
      int row = bm + ty * 4 + i;
      float v = c[i][j] + bvv;
      if (LAYOUT == 0){
        Cg[(size_t)row * Ng + col] = v;
      } else if (LAYOUT == 2){
        Cg[(size_t)col * Mg + row] = v;
      } else {
        int tok = ro + row;
        int b = tok / SS, s = tok - b * SS;
        int h = col >> 6, dh = col & 63;
        if (LAYOUT == 1) Cg[(((size_t)b * NHH + h) * SS + s) * HDD + dh] = v;
        else             Cg[(((size_t)b * NHH + h) * HDD + dh) * SS + s] = v;
      }
    }
  }
}

// ---------------- LayerNorm rows (chunked), f32 -> f32 ----------------
__global__ __launch_bounds__(256) void ln_rows_kernel(const float* __restrict__ y,
    const float* __restrict__ g, const float* __restrict__ bb,
    float* __restrict__ outf)
{
  int r = blockIdx.x, t = threadIdx.x;
  __shared__ float red[256];
  const float* row = y + (size_t)r * EE;
  float v0 = row[t], v1 = row[t + 256];
  red[t] = v0 + v1; __syncthreads();
  for (int st = 128; st > 0; st >>= 1){ if (t < st) red[t] += red[t + st]; __syncthreads(); }
  float mean = red[0] * (1.f / EE); __syncthreads();
  float d0 = v0 - mean, d1 = v1 - mean;
  red[t] = d0 * d0 + d1 * d1; __syncthreads();
  for (int st = 128; st > 0; st >>= 1){ if (t < st) red[t] += red[t + st]; __syncthreads(); }
  float rs = 1.f / sqrtf(red[0] * (1.f / EE) + 1e-5f);
  float* orow = outf + (size_t)r * EE;
  orow[t] = d0 * rs * g[t] + bb[t];
  orow[t + 256] = d1 * rs * g[t + 256] + bb[t + 256];
}

// ---------------- bqq = bq @ Wqa + bqa ----------------
__global__ __launch_bounds__(512) void bqq_kernel(const float* __restrict__ bq,
    const float* __restrict__ Wqa, const float* __restrict__ bqa, float* __restrict__ bqq)
{
  __shared__ float s[EE];
  int t = threadIdx.x;
  s[t] = bq[t]; __syncthreads();
  float a0 = 0, a1 = 0, a2 = 0, a3 = 0;
  #pragma unroll 8
  for (int k = 0; k < EE; k += 4){
    a0 += s[k]     * Wqa[(size_t)(k)     * EE + t];
    a1 += s[k + 1] * Wqa[(size_t)(k + 1) * EE + t];
    a2 += s[k + 2] * Wqa[(size_t)(k + 2) * EE + t];
    a3 += s[k + 3] * Wqa[(size_t)(k + 3) * EE + t];
  }
  bqq[t] = bqa[t] + ((a0 + a1) + (a2 + a3));
}

// ---------------- 512x512 transpose (Wo -> Wot[n][k]) ----------------
__global__ void transpose512(const float* __restrict__ src, float* __restrict__ dst)
{
  __shared__ float tile[32][33];
  int bx = blockIdx.x * 32, by = blockIdx.y * 32;
  int tx = threadIdx.x, ty = threadIdx.y;
  #pragma unroll
  for (int i = 0; i < 32; i += 8)
    tile[ty + i][tx] = src[(size_t)(by + ty + i) * 512 + bx + tx];
  __syncthreads();
  #pragma unroll
  for (int i = 0; i < 32; i += 8)
    dst[(size_t)(bx + ty + i) * 512 + by + tx] = tile[tx][ty + i];
}

// ---------------- decay -> rate ----------------
__global__ __launch_bounds__(512) void prep_decay(const float* __restrict__ dcA,
    const float* __restrict__ dcO, float* __restrict__ rA, float* __restrict__ rO)
{
  int t = threadIdx.x;
  rA[t] = expf(-fminf(fmaxf(dcA[t], 0.f), 15.f));
  rO[t] = expf(-fminf(fmaxf(dcO[t], 0.f), 15.f));
}

// ---------------- init state: act[d][b], tr[m][d][b], aA/bA/aO/bO [n][b] ----------------
__global__ __launch_bounds__(256) void init_kernel(const float* __restrict__ sa,
    const float* __restrict__ strace,
    const int* __restrict__ ol, const int* __restrict__ orr,
    float* __restrict__ act, float* __restrict__ tr,
    float* __restrict__ aA, float* __restrict__ bA,
    float* __restrict__ aO, float* __restrict__ bO)
{
  int tid = blockIdx.x * 256 + threadIdx.x;
  int b = tid >> 11, d = tid & 2047;
  act[(size_t)d * 64 + b] = sa[d];
  for (int m = 0; m < MM; m++)
    tr[((size_t)m * DD + d) * 64 + b] = strace[d * MM + m];
  if (tid < BB * NSS){
    int n = tid & (NSS - 1);
    int b2 = tid >> 9;
    aO[(size_t)n * 64 + b2] = sa[ol[n]] * sa[orr[n]];
    bO[(size_t)n * 64 + b2] = 1.f;
    aA[(size_t)n * 64 + b2] = 0.f;
    bA[(size_t)n * 64 + b2] = 0.f;
  }
}

// ---------------- the persistent cooperative step loop ----------------
struct CtmParams {
  const float *khT, *vh, *Wqqt, *bqq, *Wsyn, *bsyn, *gsyn, *bsn;
  const float *Wot, *bo, *w1, *b1, *w2, *b2, *Wout, *bout, *rA, *rO;
  const int *ial, *iar, *iol, *ior;
  float *sA, *q2e, *ao, *attnproj, *glupre, *psum, *psq, *act, *tr;
  float *aA, *bA, *aO, *bO, *so, *dout;
};

__global__ __launch_bounds__(512, 2) void ctm_loop(CtmParams p)
{
  cg::grid_group grid = cg::this_grid();
  __shared__ float sm[12800];
  const int tid = threadIdx.x, blk = blockIdx.x;
  const int lane = tid & 63, wv = tid >> 6;
  const int gw = blk * 8 + wv;                 // global wave 0..2047

  for (int t = 0; t <= TT; t++){
    // ---- P1: sA-update(t) [waves 1024..1535]; sO-update(t-1) [waves 1536..2047]
    if (t < TT && gw >= 1024 && gw < 1536){
      int n = rfl(gw - 1024);
      float r = p.rA[n];
      float pr = p.act[(size_t)p.ial[n] * 64 + lane] * p.act[(size_t)p.iar[n] * 64 + lane];
      float na = r * p.aA[(size_t)n * 64 + lane] + pr;
      float nb = r * p.bA[(size_t)n * 64 + lane] + 1.f;
      p.aA[(size_t)n * 64 + lane] = na; p.bA[(size_t)n * 64 + lane] = nb;
      p.sA[(size_t)n * 64 + lane] = na / sqrtf(nb);
    } else if (t > 0 && gw >= 1536){
      int n = rfl(gw - 1536);
      int ts = t - 1;
      float r = p.rO[n];
      float pr = p.act[(size_t)p.iol[n] * 64 + lane] * p.act[(size_t)p.ior[n] * 64 + lane];
      float na = r * p.aO[(size_t)n * 64 + lane] + pr;
      float nb = r * p.bO[(size_t)n * 64 + lane] + 1.f;
      p.aO[(size_t)n * 64 + lane] = na; p.bO[(size_t)n * 64 + lane] = nb;
      float sv = na / sqrtf(nb);
      p.so[(size_t)n * 64 + lane] = sv;
      if (ts == TT - 1) p.dout[SYNC_OFF + (size_t)lane * NSS + n] = sv;
    }
    grid.sync();

    // ---- P2: out-GEMV(t-1) [waves 0..999]; q2 = sA@Wqqt+bqq [blocks 128..255]
    if (t > 0 && gw < 1000){
      int n = rfl(gw);
      int ts = t - 1;
      const float* W = p.Wout + n;
      float a0 = 0, a1 = 0, a2 = 0, a3 = 0;
      #pragma unroll 8
      for (int k = 0; k < NSS; k += 4){
        a0 += p.so[(size_t)(k + 0) * 64 + lane] * W[(size_t)(k + 0) * OUTN];
        a1 += p.so[(size_t)(k + 1) * 64 + lane] * W[(size_t)(k + 1) * OUTN];
        a2 += p.so[(size_t)(k + 2) * 64 + lane] * W[(size_t)(k + 2) * OUTN];
        a3 += p.so[(size_t)(k + 3) * 64 + lane] * W[(size_t)(k + 3) * OUTN];
      }
      float v = p.bout[n] + ((a0 + a1) + (a2 + a3));
      p.dout[((size_t)lane * OUTN + n) * TT + ts] = v;
    } else if (t < TT && blk >= 128){
      int widx = (blk - 128) * 8 + wv;
      int e = rfl(widx >> 1);
      int ks = widx & 1;
      const float* W = p.Wqqt + (size_t)e * EE + ks * 256;
      const float* A = p.sA + (size_t)ks * 256 * 64;
      float a0 = 0, a1 = 0, a2 = 0, a3 = 0;
      #pragma unroll 8
      for (int k = 0; k < 256; k += 4){
        a0 += A[(size_t)(k + 0) * 64 + lane] * W[k + 0];
        a1 += A[(size_t)(k + 1) * 64 + lane] * W[k + 1];
        a2 += A[(size_t)(k + 2) * 64 + lane] * W[k + 2];
        a3 += A[(size_t)(k + 3) * 64 + lane] * W[k + 3];
      }
      float acc = (a0 + a1) + (a2 + a3);
      int el = wv >> 1;
      sm[(el * 2 + ks) * 64 + lane] = acc;
      __syncthreads();
      if (ks == 0){
        float v = sm[(el * 2) * 64 + lane] + sm[(el * 2 + 1) * 64 + lane] + p.bqq[e];
        p.q2e[(size_t)e * 64 + lane] = v;
      }
    }
    if (t == TT) break;
    grid.sync();

    // ---- P3: attention (2 units per block, 256 threads each)
    {
      int half = tid >> 8;
      int ut = tid & 255;
      int u = blk * 2 + half;
      int b = u >> 3, h = u & 7;
      float* qs  = sm + half * 64;
      float* ps  = sm + 128 + half * 224;
      float* red = sm + 576 + half * 256;
      if (ut < HDD) qs[ut] = p.q2e[(size_t)(h * 64 + ut) * 64 + b];
      __syncthreads();
      float sc = -1e30f;
      if (ut < SS){
        const float* K = p.khT + (size_t)u * 64 * SS + ut;
        float a0 = 0, a1 = 0, a2 = 0, a3 = 0;
        #pragma unroll 8
        for (int d2 = 0; d2 < HDD; d2 += 4){
          a0 += qs[d2 + 0] * K[(size_t)(d2 + 0) * SS];
          a1 += qs[d2 + 1] * K[(size_t)(d2 + 1) * SS];
          a2 += qs[d2 + 2] * K[(size_t)(d2 + 2) * SS];
          a3 += qs[d2 + 3] * K[(size_t)(d2 + 3) * SS];
        }
        sc = ((a0 + a1) + (a2 + a3)) * 0.125f;
      }
      red[ut] = sc; __syncthreads();
      for (int st = 128; st > 0; st >>= 1){ if (ut < st) red[ut] = fmaxf(red[ut], red[ut + st]); __syncthreads(); }
      float mx = red[0]; __syncthreads();
      float ev = 0.f;
      if (ut < SS){ ev = expf(sc - mx); ps[ut] = ev; }
      red[ut] = ev; __syncthreads();
      for (int st = 128; st > 0; st >>= 1){ if (ut < st) red[ut] += red[ut + st]; __syncthreads(); }
      float inv = 1.f / red[0]; __syncthreads();
      int dd = ut & 63, cs = ut >> 6;
      float acc = 0.f;
      for (int s2 = cs; s2 < SS; s2 += 4)
        acc += ps[s2] * p.vh[((size_t)u * SS + s2) * 64 + dd];
      red[ut] = acc; __syncthreads();
      if (ut < HDD){
        float v = red[ut] + red[64 + ut] + red[128 + ut] + red[192 + ut];
        p.ao[(size_t)(h * 64 + ut) * 64 + b] = v * inv;
      }
      __syncthreads();
    }
    grid.sync();

    // ---- P4: attnproj = ao @ Wot + bo  (all 2048 waves, ksplit 4)
    {
      int e = rfl(gw >> 2);
      int ks = gw & 3;
      const float* W = p.Wot + (size_t)e * EE + ks * 128;
      const float* A = p.ao + (size_t)ks * 128 * 64;
      float a0 = 0, a1 = 0, a2 = 0, a3 = 0;
      #pragma unroll 8
      for (int k = 0; k < 128; k += 4){
        a0 += A[(size_t)(k + 0) * 64 + lane] * W[k + 0];
        a1 += A[(size_t)(k + 1) * 64 + lane] * W[k + 1];
        a2 += A[(size_t)(k + 2) * 64 + lane] * W[k + 2];
        a3 += A[(size_t)(k + 3) * 64 + lane] * W[k + 3];
      }
      float acc = (a0 + a1) + (a2 + a3);
      int el = wv >> 2;
      sm[(el * 4 + ks) * 64 + lane] = acc;
      __syncthreads();
      if (ks == 0){
        float v = sm[(el * 4) * 64 + lane] + sm[(el * 4 + 1) * 64 + lane]
                + sm[(el * 4 + 2) * 64 + lane] + sm[(el * 4 + 3) * 64 + lane] + p.bo[e];
        p.attnproj[(size_t)e * 64 + lane] = v;
      }
      __syncthreads();
    }
    grid.sync();

    // ---- P5: synapse GEMM + GLU + LN-partials
    {
      int pairIdx = wv & 3, myHalf = wv >> 2;
      int bp = lane & 31;
      int c = blk * 8 + pairIdx * 2 + (lane >> 5) + myHalf * 2048;
      float2 e0 = {0.f, 0.f}, e1 = {0.f, 0.f};
      const float* A1 = p.attnproj + bp * 2;
      const float* A2 = p.act + bp * 2;
      const float* W = p.Wsyn + c;
      #pragma unroll 4
      for (int k = 0; k < 512; k += 2){
        float2 av0 = *reinterpret_cast<const float2*>(A1 + (size_t)k * 64);
        float2 av1 = *reinterpret_cast<const float2*>(A1 + (size_t)(k + 1) * 64);
        float w0 = W[(size_t)k * NSYN], w1v = W[(size_t)(k + 1) * NSYN];
        e0.x += av0.x * w0; e0.y += av0.y * w0;
        e1.x += av1.x * w1v; e1.y += av1.y * w1v;
      }
      #pragma unroll 4
      for (int k = 0; k < 2048; k += 2){
        float2 av0 = *reinterpret_cast<const float2*>(A2 + (size_t)k * 64);
        float2 av1 = *reinterpret_cast<const float2*>(A2 + (size_t)(k + 1) * 64);
        float w0 = W[(size_t)(k + 512) * NSYN], w1v = W[(size_t)(k + 513) * NSYN];
        e0.x += av0.x * w0; e0.y += av0.y * w0;
        e1.x += av1.x * w1v; e1.y += av1.y * w1v;
      }
      float bs = p.bsyn[c];
      float2 acc; acc.x = e0.x + e1.x + bs; acc.y = e0.y + e1.y + bs;
      float2* sh = reinterpret_cast<float2*>(sm);
      int ci = pairIdx * 2 + (lane >> 5) + myHalf * 8;
      sh[ci * 32 + bp] = acc;
      __syncthreads();
      if (myHalf == 0){
        float2 x1 = sh[(ci + 8) * 32 + bp];
        float2 u;
        u.x = acc.x * sigm(x1.x);
        u.y = acc.y * sigm(x1.y);
        *reinterpret_cast<float2*>(&p.glupre[(size_t)c * 64 + bp * 2]) = u;
        sh[ci * 32 + bp] = u;
        float2 uq; uq.x = u.x * u.x; uq.y = u.y * u.y;
        sh[(ci + 8) * 32 + bp] = uq;
      }
      __syncthreads();
      if (wv == 0){
        int sel = lane >> 5;
        float2 s = {0.f, 0.f};
        #pragma unroll
        for (int i = 0; i < 8; i++){
          float2 v = sh[(i + sel * 8) * 32 + bp];
          s.x += v.x; s.y += v.y;
        }
        float* dst = sel ? p.psq : p.psum;
        *reinterpret_cast<float2*>(&dst[(size_t)blk * 64 + bp * 2]) = s;
      }
      __syncthreads();
    }
    grid.sync();

    // ---- P6: LN finalize -> trace slot   (wave = d, lane = b)
    {
      int d = rfl(gw);
      float s0 = 0, s1 = 0, q0 = 0, q1 = 0;
      #pragma unroll 8
      for (int i = 0; i < 256; i += 2){
        s0 += p.psum[(size_t)(i) * 64 + lane];
        s1 += p.psum[(size_t)(i + 1) * 64 + lane];
        q0 += p.psq[(size_t)(i) * 64 + lane];
        q1 += p.psq[(size_t)(i + 1) * 64 + lane];
      }
      float mean = (s0 + s1) * (1.f / DD);
      float var = (q0 + q1) * (1.f / DD) - mean * mean;
      float rs = 1.f / sqrtf(var + 1e-5f);
      float u = p.glupre[(size_t)d * 64 + lane];
      int slot = t % MM;
      p.tr[((size_t)slot * DD + d) * 64 + lane] = (u - mean) * rs * p.gsyn[d] + p.bsn[d];
    }
    grid.sync();

    // ---- P7: per-neuron MLP  (block = 8 d's; wave = d, lane = b; w1 slice in LDS)
    {
      int d0 = blk * 8;
      for (int idx = tid; idx < 1600; idx += 512){
        float4 va = *reinterpret_cast<const float4*>(p.w1 + (size_t)idx * DD + d0);
        float4 vb = *reinterpret_cast<const float4*>(p.w1 + (size_t)idx * DD + d0 + 4);
        sm[0 * 1600 + idx] = va.x; sm[1 * 1600 + idx] = va.y;
        sm[2 * 1600 + idx] = va.z; sm[3 * 1600 + idx] = va.w;
        sm[4 * 1600 + idx] = vb.x; sm[5 * 1600 + idx] = vb.y;
        sm[6 * 1600 + idx] = vb.z; sm[7 * 1600 + idx] = vb.w;
      }
      __syncthreads();
      int dd = wv;
      int d = d0 + dd;
      float hp[64];
      #pragma unroll
      for (int h = 0; h < 64; h++) hp[h] = p.b1[(size_t)d * 64 + h];
      for (int j = 0; j < MM; j++){
        int slot = (t + 1 + j) % MM;
        float tv = p.tr[((size_t)slot * DD + d) * 64 + lane];
        const float* wr = &sm[dd * 1600 + j * 64];
        #pragma unroll
        for (int h4 = 0; h4 < 16; h4++){
          float4 w = *reinterpret_cast<const float4*>(&wr[h4 * 4]);
          hp[h4 * 4 + 0] += tv * w.x;
          hp[h4 * 4 + 1] += tv * w.y;
          hp[h4 * 4 + 2] += tv * w.z;
          hp[h4 * 4 + 3] += tv * w.w;
        }
      }
      float o0 = p.b2[(size_t)d * 2], o1 = p.b2[(size_t)d * 2 + 1];
      #pragma unroll
      for (int h2 = 0; h2 < HNN; h2++){
        float hh = hp[h2] * sigm(hp[h2 + HNN]);
        o0 += hh * p.w2[((size_t)(h2 * 2)) * DD + d];
        o1 += hh * p.w2[((size_t)(h2 * 2 + 1)) * DD + d];
      }
      p.act[(size_t)d * 64 + lane] = o0 * sigm(o1);
      __syncthreads();
    }
    grid.sync();
  }
}

// ---------------- certainty from stored predictions ----------------
__global__ __launch_bounds__(256) void cert_kernel(float* __restrict__ dout)
{
  int blk = blockIdx.x;
  int b = blk / TT, t = blk % TT;
  int tid = threadIdx.x;
  __shared__ float red[256];
  float vals[4];
  float mx = -1e30f;
  #pragma unroll
  for (int i = 0; i < 4; i++){
    int n = tid + i * 256;
    float v = (n < OUTN) ? dout[((size_t)b * OUTN + n) * TT + t] : -1e30f;
    vals[i] = v; mx = fmaxf(mx, v);
  }
  red[tid] = mx; __syncthreads();
  for (int st = 128; st > 0; st >>= 1){ if (tid < st) red[tid] = fmaxf(red[tid], red[tid + st]); __syncthreads(); }
  mx = red[0]; __syncthreads();
  float z = 0.f, s1 = 0.f;
  #pragma unroll
  for (int i = 0; i < 4; i++){
    int n = tid + i * 256;
    if (n < OUTN){
      float e = expf(vals[i] - mx);
      z += e; s1 += e * (vals[i] - mx);
    }
  }
  red[tid] = z; __syncthreads();
  for (int st = 128; st > 0; st >>= 1){ if (tid < st) red[tid] += red[tid + st]; __syncthreads(); }
  z = red[0]; __syncthreads();
  red[tid] = s1; __syncthreads();
  for (int st = 128; st > 0; st >>= 1){ if (tid < st) red[tid] += red[tid + st]; __syncthreads(); }
  s1 = red[0];
  if (tid == 0){
    float ne = (logf(z) - s1 / z) * (1.f / logf(1000.f));
    dout[CERT_OFF + ((size_t)b * 2 + 0) * TT + t] = ne;
    dout[CERT_OFF + ((size_t)b * 2 + 1) * TT + t] = 1.f - ne;
  }
}

extern "C" void kernel_launch(void* const* d_in, const int* in_sizes, int n_in,
                              void* d_out, int out_size, void* d_ws, size_t ws_size,
                              hipStream_t stream)
{
  const float* x    = (const float*)d_in[0];
  const float* Wkv  = (const float*)d_in[1];
  const float* bkv  = (const float*)d_in[2];
  const float* gkv  = (const float*)d_in[3];
  const float* bkv2 = (const float*)d_in[4];
  const float* Wq   = (const float*)d_in[5];
  const float* bq   = (const float*)d_in[6];
  const float* Wqa  = (const float*)d_in[7];
  const float* bqa  = (const float*)d_in[8];
  const float* Wka  = (const float*)d_in[9];
  const float* bka  = (const float*)d_in[10];
  const float* Wva  = (const float*)d_in[11];
  const float* bva  = (const float*)d_in[12];
  const float* Wo   = (const float*)d_in[13];
  const float* bo   = (const float*)d_in[14];
  const float* Wsyn = (const float*)d_in[15];
  const float* bsyn = (const float*)d_in[16];
  const float* gsyn = (const float*)d_in[17];
  const float* bsn  = (const float*)d_in[18];
  const float* w1   = (const float*)d_in[19];
  const float* b1   = (const float*)d_in[20];
  const float* w2   = (const float*)d_in[21];
  const float* b2   = (const float*)d_in[22];
  const float* sact = (const float*)d_in[23];
  const float* strc = (const float*)d_in[24];
  const float* dcA  = (const float*)d_in[25];
  const float* dcO  = (const float*)d_in[26];
  const float* Wout = (const float*)d_in[27];
  const float* bout = (const float*)d_in[28];
  const int* ial = (const int*)d_in[29];
  const int* iar = (const int*)d_in[30];
  const int* iol = (const int*)d_in[31];
  const int* ior = (const int*)d_in[32];

  char* ws = (char*)d_ws;
  float* khT  = (float*)(ws + 0);          // 25,690,112 B
  float* vh   = (float*)(ws + 25690112);   // 25,690,112 B
  // precompute scratch (dead before step-state written):
  float* B0   = (float*)(ws + 51380224);   // 6,422,528 B (kvn pre-LN chunk)
  float* B1   = (float*)(ws + 57802752);   // 6,422,528 B (kvn post-LN chunk)
  // step-time region (overlays B0/B1):
  float* tr       = (float*)(ws + 51380224);   // 13,107,200
  float* act      = (float*)(ws + 64487424);   // 524,288
  float* sA       = (float*)(ws + 65011712);   // 131,072
  float* q2e      = (float*)(ws + 65142784);   // 131,072
  float* ao       = (float*)(ws + 65273856);   // 131,072
  float* attnproj = (float*)(ws + 65404928);   // 131,072
  float* glupre   = (float*)(ws + 65536000);   // 524,288
  float* psum     = (float*)(ws + 66060288);   // 65,536
  float* psq      = (float*)(ws + 66125824);   // 65,536
  float* aA       = (float*)(ws + 66191360);   // 131,072
  float* bA       = (float*)(ws + 66322432);   // 131,072
  float* aO       = (float*)(ws + 66453504);   // 131,072
  float* bO       = (float*)(ws + 66584576);   // 131,072
  float* so       = (float*)(ws + 66715648);   // 131,072
  float* Wqqt     = (float*)(ws + 66846720);   // 1,048,576
  float* Wot      = (float*)(ws + 67895296);   // 1,048,576
  float* bqqb     = (float*)(ws + 68943872);   // 2,048
  float* rA       = (float*)(ws + 68945920);   // 2,048
  float* rO       = (float*)(ws + 68947968);   // 2,048
  float* dout = (float*)d_out;

  // precompute kv -> khT / vh in 4 row-chunks of 3136 (scratch aliases step region)
  for (int c = 0; c < 4; c++){
    const float* xc = x + (size_t)c * 3136 * EE;
    sgemm<0><<<dim3(49, 8), 256, 0, stream>>>(xc, Wkv, bkv, B0, 3136, EE, EE, 0);
    ln_rows_kernel<<<3136, 256, 0, stream>>>(B0, gkv, bkv2, B1);
    sgemm<3><<<dim3(49, 8), 256, 0, stream>>>(B1, Wka, bka, khT, 3136, EE, EE, c * 3136);
    sgemm<1><<<dim3(49, 8), 256, 0, stream>>>(B1, Wva, bva, vh, 3136, EE, EE, c * 3136);
  }
  // folded query weights: Wqqt[e][k] = (Wq@Wqa)^T ; bqq = bq@Wqa + bqa
  sgemm<2><<<dim3(8, 8), 256, 0, stream>>>(Wq, Wqa, nullptr, Wqqt, EE, EE, EE, 0);
  bqq_kernel<<<1, 512, 0, stream>>>(bq, Wqa, bqa, bqqb);
  transpose512<<<dim3(16, 16), dim3(32, 8), 0, stream>>>(Wo, Wot);
  prep_decay<<<1, 512, 0, stream>>>(dcA, dcO, rA, rO);
  init_kernel<<<512, 256, 0, stream>>>(sact, strc, iol, ior, act, tr, aA, bA, aO, bO);

  CtmParams prm;
  prm.khT = khT; prm.vh = vh; prm.Wqqt = Wqqt; prm.bqq = bqqb;
  prm.Wsyn = Wsyn; prm.bsyn = bsyn; prm.gsyn = gsyn; prm.bsn = bsn;
  prm.Wot = Wot; prm.bo = bo; prm.w1 = w1; prm.b1 = b1; prm.w2 = w2; prm.b2 = b2;
  prm.Wout = Wout; prm.bout = bout; prm.rA = rA; prm.rO = rO;
  prm.ial = ial; prm.iar = iar; prm.iol = iol; prm.ior = ior;
  prm.sA = sA; prm.q2e = q2e; prm.ao = ao; prm.attnproj = attnproj;
  prm.glupre = glupre; prm.psum = psum; prm.psq = psq; prm.act = act; prm.tr = tr;
  prm.aA = aA; prm.bA = bA; prm.aO = aO; prm.bO = bO; prm.so = so; prm.dout = dout;

  void* kargs[1] = { &prm };
  hipLaunchCooperativeKernel((const void*)ctm_loop, dim3(256), dim3(512), kargs, 0, stream);

  cert_kernel<<<BB * TT, 256, 0, stream>>>(dout);
}

// Round 7
// 8624.878 us; speedup vs baseline: 4.3158x; 4.3158x over previous
//
#include <hip/hip_runtime.h>

#define BB 64
#define SS 196
#define EE 512
#define DD 2048
#define MM 25
#define HNN 32
#define NHH 8
#define TT 50
#define NSS 512
#define OUTN 1000
#define HDD 64
#define KSYN 2560
#define NSYN 4096

#define CERT_OFF 3200000
#define SYNC_OFF 3206400

__device__ __forceinline__ float sigm(float x){ return 1.f / (1.f + expf(-x)); }
__device__ __forceinline__ int rfl(int x){ return __builtin_amdgcn_readfirstlane(x); }

// ---------------- f32 GEMM (precompute): C = A(M,K) @ W(K,N) + bias ----------------
// LAYOUT 0: row-major. 1: vh permute ((b*8+h)*196+s)*64+d. 2: transposed C[col][row].
// 3: khT permute ((b*8+h)*64+d)*196+s.  ro = global row offset for layouts 1/3.
template<int LAYOUT>
__global__ __launch_bounds__(256) void sgemm(
    const float* __restrict__ Ag, const float* __restrict__ Wg,
    const float* __restrict__ bias, float* __restrict__ Cg,
    int Mg, int Ng, int Kg, int ro)
{
  __shared__ float As[16][68];
  __shared__ float Bs[16][68];
  int t = threadIdx.x;
  int bm = blockIdx.x * 64, bn = blockIdx.y * 64;
  int ty = t >> 4, tx = t & 15;
  int atm = t >> 2, atk = (t & 3) * 4;
  int bkk = t >> 4, bnn = (t & 15) * 4;
  float c[4][4] = {};
  for (int k0 = 0; k0 < Kg; k0 += 16){
    float4 av = *reinterpret_cast<const float4*>(Ag + (size_t)(bm + atm) * Kg + k0 + atk);
    As[atk][atm] = av.x; As[atk + 1][atm] = av.y;
    As[atk + 2][atm] = av.z; As[atk + 3][atm] = av.w;
    float4 bv = *reinterpret_cast<const float4*>(Wg + (size_t)(k0 + bkk) * Ng + bn + bnn);
    *reinterpret_cast<float4*>(&Bs[bkk][bnn]) = bv;
    __syncthreads();
    #pragma unroll
    for (int k = 0; k < 16; k++){
      float4 a = *reinterpret_cast<const float4*>(&As[k][ty * 4]);
      float4 b = *reinterpret_cast<const float4*>(&Bs[k][tx * 4]);
      c[0][0] += a.x * b.x; c[0][1] += a.x * b.y; c[0][2] += a.x * b.z; c[0][3] += a.x * b.w;
      c[1][0] += a.y * b.x; c[1][1] += a.y * b.y; c[1][2] += a.y * b.z; c[1][3] += a.y * b.w;
      c[2][0] += a.z * b.x; c[2][1] += a.z * b.y; c[2][2] += a.z * b.z; c[2][3] += a.z * b.w;
      c[3][0] += a.w * b.x; c[3][1] += a.w * b.y; c[3][2] += a.w * b.z; c[3][3] += a.w * b.w;
    }
    __syncthreads();
  }
  #pragma unroll
  for (int j = 0; j < 4; j++){
    int col = bn + tx * 4 + j;
    float bvv = bias ? bias[col] : 0.f;
    #pragma unroll
    for (int i = 0; i < 4; i++){
      int row = bm + ty * 4 + i;
      float v = c[i][j] + bvv;
      if (LAYOUT == 0){
        Cg[(size_t)row * Ng + col] = v;
      } else if (LAYOUT == 2){
        Cg[(size_t)col * Mg + row] = v;
      } else {
        int tok = ro + row;
        int b = tok / SS, s = tok - b * SS;
        int h = col >> 6, dh = col & 63;
        if (LAYOUT == 1) Cg[(((size_t)b * NHH + h) * SS + s) * HDD + dh] = v;
        else             Cg[(((size_t)b * NHH + h) * HDD + dh) * SS + s] = v;
      }
    }
  }
}

// ---------------- LayerNorm rows (chunked), f32 -> f32 ----------------
__global__ __launch_bounds__(256) void ln_rows_kernel(const float* __restrict__ y,
    const float* __restrict__ g, const float* __restrict__ bb,
    float* __restrict__ outf)
{
  int r = blockIdx.x, t = threadIdx.x;
  __shared__ float red[256];
  const float* row = y + (size_t)r * EE;
  float v0 = row[t], v1 = row[t + 256];
  red[t] = v0 + v1; __syncthreads();
  for (int st = 128; st > 0; st >>= 1){ if (t < st) red[t] += red[t + st]; __syncthreads(); }
  float mean = red[0] * (1.f / EE); __syncthreads();
  float d0 = v0 - mean, d1 = v1 - mean;
  red[t] = d0 * d0 + d1 * d1; __syncthreads();
  for (int st = 128; st > 0; st >>= 1){ if (t < st) red[t] += red[t + st]; __syncthreads(); }
  float rs = 1.f / sqrtf(red[0] * (1.f / EE) + 1e-5f);
  float* orow = outf + (size_t)r * EE;
  orow[t] = d0 * rs * g[t] + bb[t];
  orow[t + 256] = d1 * rs * g[t + 256] + bb[t + 256];
}

// ---------------- bqq = bq @ Wqa + bqa ----------------
__global__ __launch_bounds__(512) void bqq_kernel(const float* __restrict__ bq,
    const float* __restrict__ Wqa, const float* __restrict__ bqa, float* __restrict__ bqq)
{
  __shared__ float s[EE];
  int t = threadIdx.x;
  s[t] = bq[t]; __syncthreads();
  float a0 = 0, a1 = 0, a2 = 0, a3 = 0;
  #pragma unroll 8
  for (int k = 0; k < EE; k += 4){
    a0 += s[k]     * Wqa[(size_t)(k)     * EE + t];
    a1 += s[k + 1] * Wqa[(size_t)(k + 1) * EE + t];
    a2 += s[k + 2] * Wqa[(size_t)(k + 2) * EE + t];
    a3 += s[k + 3] * Wqa[(size_t)(k + 3) * EE + t];
  }
  bqq[t] = bqa[t] + ((a0 + a1) + (a2 + a3));
}

// ---------------- generic transpose: src[M][N] -> dst[N][M] ----------------
__global__ void transposeMN(const float* __restrict__ src, float* __restrict__ dst,
                            int M, int N)
{
  __shared__ float tile[32][33];
  int bx = blockIdx.x * 32;   // N dim
  int by = blockIdx.y * 32;   // M dim
  int tx = threadIdx.x, ty = threadIdx.y;
  #pragma unroll
  for (int i = 0; i < 32; i += 8){
    int r = by + ty + i, c = bx + tx;
    if (r < M && c < N) tile[ty + i][tx] = src[(size_t)r * N + c];
  }
  __syncthreads();
  #pragma unroll
  for (int i = 0; i < 32; i += 8){
    int r = bx + ty + i, c = by + tx;
    if (r < N && c < M) dst[(size_t)r * M + c] = tile[tx][ty + i];
  }
}

// ---------------- decay -> rate ----------------
__global__ __launch_bounds__(512) void prep_decay(const float* __restrict__ dcA,
    const float* __restrict__ dcO, float* __restrict__ rA, float* __restrict__ rO)
{
  int t = threadIdx.x;
  rA[t] = expf(-fminf(fmaxf(dcA[t], 0.f), 15.f));
  rO[t] = expf(-fminf(fmaxf(dcO[t], 0.f), 15.f));
}

// ---------------- init state ----------------
__global__ __launch_bounds__(256) void init_kernel(const float* __restrict__ sa,
    const float* __restrict__ strace,
    const int* __restrict__ ol, const int* __restrict__ orr,
    float* __restrict__ act, float* __restrict__ tr,
    float* __restrict__ aA, float* __restrict__ bA,
    float* __restrict__ aO, float* __restrict__ bO)
{
  int tid = blockIdx.x * 256 + threadIdx.x;
  int b = tid >> 11, d = tid & 2047;
  act[(size_t)d * 64 + b] = sa[d];
  for (int m = 0; m < MM; m++)
    tr[((size_t)m * DD + d) * 64 + b] = strace[d * MM + m];
  if (tid < BB * NSS){
    int n = tid & (NSS - 1);
    int b2 = tid >> 9;
    aO[(size_t)n * 64 + b2] = sa[ol[n]] * sa[orr[n]];
    bO[(size_t)n * 64 + b2] = 1.f;
    aA[(size_t)n * 64 + b2] = 0.f;
    bA[(size_t)n * 64 + b2] = 0.f;
  }
}

// ---------------- K1: sA(t) [waves 0..511] + sO(t-1) [waves 512..1023] ----------------
__global__ __launch_bounds__(512) void k_sync(const float* __restrict__ act,
    float* __restrict__ aA, float* __restrict__ bA,
    float* __restrict__ aO, float* __restrict__ bO,
    float* __restrict__ sA, float* __restrict__ so,
    const float* __restrict__ rA, const float* __restrict__ rO,
    const int* __restrict__ ial, const int* __restrict__ iar,
    const int* __restrict__ iol, const int* __restrict__ ior,
    float* __restrict__ dout, int t)
{
  int lane = threadIdx.x & 63, wv = threadIdx.x >> 6;
  int gw = blockIdx.x * 8 + wv;
  if (t < TT && gw < 512){
    int n = rfl(gw);
    float r = rA[n];
    float pr = act[(size_t)ial[n] * 64 + lane] * act[(size_t)iar[n] * 64 + lane];
    float na = r * aA[(size_t)n * 64 + lane] + pr;
    float nb = r * bA[(size_t)n * 64 + lane] + 1.f;
    aA[(size_t)n * 64 + lane] = na; bA[(size_t)n * 64 + lane] = nb;
    sA[(size_t)n * 64 + lane] = na / sqrtf(nb);
  } else if (t > 0 && gw >= 512){
    int n = rfl(gw - 512);
    float r = rO[n];
    float pr = act[(size_t)iol[n] * 64 + lane] * act[(size_t)ior[n] * 64 + lane];
    float na = r * aO[(size_t)n * 64 + lane] + pr;
    float nb = r * bO[(size_t)n * 64 + lane] + 1.f;
    aO[(size_t)n * 64 + lane] = na; bO[(size_t)n * 64 + lane] = nb;
    float sv = na / sqrtf(nb);
    so[(size_t)n * 64 + lane] = sv;
    if (t - 1 == TT - 1) dout[SYNC_OFF + (size_t)lane * NSS + n] = sv;
  }
}

// ---------------- K2: q2 GEMV [blocks 0..127] ; out GEMV(t-1) [blocks 128..255] ----------------
__global__ __launch_bounds__(512) void k_gemv2(const float* __restrict__ sA,
    const float* __restrict__ Wqqt, const float* __restrict__ bqq,
    const float* __restrict__ so, const float* __restrict__ WoutT,
    const float* __restrict__ bout,
    float* __restrict__ q2e, float* __restrict__ dout, int t)
{
  __shared__ float red[4][2][64];
  int lane = threadIdx.x & 63, wv = threadIdx.x >> 6;
  int blk = blockIdx.x;
  if (blk < 128){
    if (t >= TT) return;
    int widx = blk * 8 + wv;
    int e = rfl(widx >> 1);
    int ks = widx & 1;
    const float* W = Wqqt + (size_t)e * EE + ks * 256;
    const float* A = sA + (size_t)ks * 256 * 64;
    float a0 = 0, a1 = 0, a2 = 0, a3 = 0;
    #pragma unroll 8
    for (int k = 0; k < 256; k += 4){
      a0 += A[(size_t)(k + 0) * 64 + lane] * W[k + 0];
      a1 += A[(size_t)(k + 1) * 64 + lane] * W[k + 1];
      a2 += A[(size_t)(k + 2) * 64 + lane] * W[k + 2];
      a3 += A[(size_t)(k + 3) * 64 + lane] * W[k + 3];
    }
    red[wv >> 1][ks][lane] = (a0 + a1) + (a2 + a3);
    __syncthreads();
    if (ks == 0){
      q2e[(size_t)e * 64 + lane] = red[wv >> 1][0][lane] + red[wv >> 1][1][lane] + bqq[e];
    }
  } else {
    if (t == 0) return;
    int nw = (blk - 128) * 8 + wv;
    if (nw >= OUTN) return;
    int n = rfl(nw);
    int ts = t - 1;
    const float* W = WoutT + (size_t)n * EE;
    float a0 = 0, a1 = 0, a2 = 0, a3 = 0;
    #pragma unroll 8
    for (int k = 0; k < NSS; k += 4){
      a0 += so[(size_t)(k + 0) * 64 + lane] * W[k + 0];
      a1 += so[(size_t)(k + 1) * 64 + lane] * W[k + 1];
      a2 += so[(size_t)(k + 2) * 64 + lane] * W[k + 2];
      a3 += so[(size_t)(k + 3) * 64 + lane] * W[k + 3];
    }
    dout[((size_t)lane * OUTN + n) * TT + ts] = bout[n] + ((a0 + a1) + (a2 + a3));
  }
}

// ---------------- K3: attention (2 (b,h) units per block) ----------------
__global__ __launch_bounds__(512) void k_attn(const float* __restrict__ q2e,
    const float* __restrict__ khT, const float* __restrict__ vh,
    float* __restrict__ ao)
{
  __shared__ float qs[2][64];
  __shared__ float ps[2][224];
  __shared__ float red[2][256];
  int tid = threadIdx.x, blk = blockIdx.x;
  int half = tid >> 8, ut = tid & 255;
  int u = blk * 2 + half;
  int b = u >> 3, h = u & 7;
  if (ut < HDD) qs[half][ut] = q2e[(size_t)(h * 64 + ut) * 64 + b];
  __syncthreads();
  float sc = -1e30f;
  if (ut < SS){
    const float* K = khT + (size_t)u * 64 * SS + ut;
    float a0 = 0, a1 = 0, a2 = 0, a3 = 0;
    #pragma unroll 8
    for (int d2 = 0; d2 < HDD; d2 += 4){
      a0 += qs[half][d2 + 0] * K[(size_t)(d2 + 0) * SS];
      a1 += qs[half][d2 + 1] * K[(size_t)(d2 + 1) * SS];
      a2 += qs[half][d2 + 2] * K[(size_t)(d2 + 2) * SS];
      a3 += qs[half][d2 + 3] * K[(size_t)(d2 + 3) * SS];
    }
    sc = ((a0 + a1) + (a2 + a3)) * 0.125f;
  }
  red[half][ut] = sc; __syncthreads();
  for (int st = 128; st > 0; st >>= 1){ if (ut < st) red[half][ut] = fmaxf(red[half][ut], red[half][ut + st]); __syncthreads(); }
  float mx = red[half][0]; __syncthreads();
  float ev = 0.f;
  if (ut < SS){ ev = expf(sc - mx); ps[half][ut] = ev; }
  red[half][ut] = ev; __syncthreads();
  for (int st = 128; st > 0; st >>= 1){ if (ut < st) red[half][ut] += red[half][ut + st]; __syncthreads(); }
  float inv = 1.f / red[half][0]; __syncthreads();
  int dd = ut & 63, cs = ut >> 6;
  float acc = 0.f;
  for (int s2 = cs; s2 < SS; s2 += 4)
    acc += ps[half][s2] * vh[((size_t)u * SS + s2) * 64 + dd];
  red[half][ut] = acc; __syncthreads();
  if (ut < HDD){
    float v = red[half][ut] + red[half][64 + ut] + red[half][128 + ut] + red[half][192 + ut];
    ao[(size_t)(h * 64 + ut) * 64 + b] = v * inv;
  }
}

// ---------------- K4: attnproj = ao @ Wot + bo (ksplit 4) ----------------
__global__ __launch_bounds__(512) void k_wo(const float* __restrict__ ao,
    const float* __restrict__ Wot, const float* __restrict__ bo,
    float* __restrict__ attnproj)
{
  __shared__ float red[2][4][64];
  int lane = threadIdx.x & 63, wv = threadIdx.x >> 6;
  int gw = blockIdx.x * 8 + wv;
  int e = rfl(gw >> 2);
  int ks = gw & 3;
  const float* W = Wot + (size_t)e * EE + ks * 128;
  const float* A = ao + (size_t)ks * 128 * 64;
  float a0 = 0, a1 = 0, a2 = 0, a3 = 0;
  #pragma unroll 8
  for (int k = 0; k < 128; k += 4){
    a0 += A[(size_t)(k + 0) * 64 + lane] * W[k + 0];
    a1 += A[(size_t)(k + 1) * 64 + lane] * W[k + 1];
    a2 += A[(size_t)(k + 2) * 64 + lane] * W[k + 2];
    a3 += A[(size_t)(k + 3) * 64 + lane] * W[k + 3];
  }
  red[wv >> 2][ks][lane] = (a0 + a1) + (a2 + a3);
  __syncthreads();
  if (ks == 0){
    int el = wv >> 2;
    attnproj[(size_t)e * 64 + lane] = red[el][0][lane] + red[el][1][lane]
                                    + red[el][2][lane] + red[el][3][lane] + bo[e];
  }
}

// ---------------- K5: synapse GEMM + GLU + LN partials ----------------
// A = [2560][64] contiguous (attnproj||act). Block bn: GLU pairs (bn*8+ci, 2048+bn*8+ci).
__global__ __launch_bounds__(512) void k_syn(const float* __restrict__ A,
    const float* __restrict__ Wsyn, const float* __restrict__ bsyn,
    float* __restrict__ glupre, float* __restrict__ psum, float* __restrict__ psq)
{
  __shared__ float red[8][16][64];
  int tid = threadIdx.x, bn = blockIdx.x;
  int lane = tid & 63, wv = tid >> 6;
  int c0 = bn * 8;
  const float* Wl = Wsyn + c0;
  const float* Wh = Wsyn + 2048 + c0;
  float acc[16];
  #pragma unroll
  for (int i = 0; i < 16; i++) acc[i] = 0.f;
  int kb = rfl(wv * 320);
  #pragma unroll 4
  for (int k = kb; k < kb + 320; k++){
    float a = A[(size_t)k * 64 + lane];
    const float* wl = Wl + (size_t)k * NSYN;
    const float* wh = Wh + (size_t)k * NSYN;
    #pragma unroll
    for (int ci = 0; ci < 8; ci++){
      acc[ci]     += a * wl[ci];
      acc[8 + ci] += a * wh[ci];
    }
  }
  #pragma unroll
  for (int i = 0; i < 16; i++) red[wv][i][lane] = acc[i];
  __syncthreads();
  {
    int ci = tid >> 6;   // 0..7
    int b = lane;
    float x0 = 0.f, x1 = 0.f;
    #pragma unroll
    for (int w = 0; w < 8; w++){ x0 += red[w][ci][b]; x1 += red[w][8 + ci][b]; }
    x0 += bsyn[c0 + ci]; x1 += bsyn[2048 + c0 + ci];
    float u = x0 * sigm(x1);
    glupre[(size_t)(c0 + ci) * 64 + b] = u;
    red[0][ci][b] = u;
  }
  __syncthreads();
  if (tid < 64){
    float s = 0.f, q = 0.f;
    #pragma unroll
    for (int ci = 0; ci < 8; ci++){
      float u = red[0][ci][tid];
      s += u; q += u * u;
    }
    psum[(size_t)bn * 64 + tid] = s;
    psq[(size_t)bn * 64 + tid] = q;
  }
}

// ---------------- K6: LN finalize + per-neuron MLP (block = 8 d's) ----------------
__global__ __launch_bounds__(512) void k_nlm(const float* __restrict__ glupre,
    const float* __restrict__ psum, const float* __restrict__ psq,
    const float* __restrict__ gsyn, const float* __restrict__ bsn,
    const float* __restrict__ w1, const float* __restrict__ b1,
    const float* __restrict__ w2, const float* __restrict__ b2,
    float* __restrict__ tr, float* __restrict__ act, int t)
{
  __shared__ float w1s[8 * 1600];
  __shared__ float rs1[8][64];
  __shared__ float rs2[8][64];
  __shared__ float mrs[128];
  int tid = threadIdx.x, bn = blockIdx.x;
  int lane = tid & 63, wv = tid >> 6;
  int d0 = bn * 8;
  // stage w1 slice (8 d's)
  for (int idx = tid; idx < 1600; idx += 512){
    float4 va = *reinterpret_cast<const float4*>(w1 + (size_t)idx * DD + d0);
    float4 vb = *reinterpret_cast<const float4*>(w1 + (size_t)idx * DD + d0 + 4);
    w1s[0 * 1600 + idx] = va.x; w1s[1 * 1600 + idx] = va.y;
    w1s[2 * 1600 + idx] = va.z; w1s[3 * 1600 + idx] = va.w;
    w1s[4 * 1600 + idx] = vb.x; w1s[5 * 1600 + idx] = vb.y;
    w1s[6 * 1600 + idx] = vb.z; w1s[7 * 1600 + idx] = vb.w;
  }
  // redundant per-block LN stats reduce
  {
    float s = 0.f, q = 0.f;
    for (int i = wv * 32; i < wv * 32 + 32; i++){
      s += psum[(size_t)i * 64 + lane];
      q += psq[(size_t)i * 64 + lane];
    }
    rs1[wv][lane] = s; rs2[wv][lane] = q;
  }
  __syncthreads();
  if (tid < 64){
    float ts = 0.f, tq = 0.f;
    #pragma unroll
    for (int w = 0; w < 8; w++){ ts += rs1[w][tid]; tq += rs2[w][tid]; }
    float mean = ts * (1.f / DD);
    float var = tq * (1.f / DD) - mean * mean;
    mrs[tid] = mean;
    mrs[64 + tid] = 1.f / sqrtf(var + 1e-5f);
  }
  __syncthreads();
  int d = d0 + wv;
  float mean = mrs[lane], rsv = mrs[64 + lane];
  float u = glupre[(size_t)d * 64 + lane];
  float snew = (u - mean) * rsv * gsyn[d] + bsn[d];
  int slot = t % MM;
  tr[((size_t)slot * DD + d) * 64 + lane] = snew;
  float hp[64];
  #pragma unroll
  for (int h = 0; h < 64; h++) hp[h] = b1[(size_t)d * 64 + h];
  for (int j = 0; j < MM - 1; j++){
    int js = (t + 1 + j) % MM;
    float tv = tr[((size_t)js * DD + d) * 64 + lane];
    const float* wr = &w1s[wv * 1600 + j * 64];
    #pragma unroll
    for (int h4 = 0; h4 < 16; h4++){
      float4 w = *reinterpret_cast<const float4*>(&wr[h4 * 4]);
      hp[h4 * 4 + 0] += tv * w.x;
      hp[h4 * 4 + 1] += tv * w.y;
      hp[h4 * 4 + 2] += tv * w.z;
      hp[h4 * 4 + 3] += tv * w.w;
    }
  }
  {
    const float* wr = &w1s[wv * 1600 + 24 * 64];
    #pragma unroll
    for (int h4 = 0; h4 < 16; h4++){
      float4 w = *reinterpret_cast<const float4*>(&wr[h4 * 4]);
      hp[h4 * 4 + 0] += snew * w.x;
      hp[h4 * 4 + 1] += snew * w.y;
      hp[h4 * 4 + 2] += snew * w.z;
      hp[h4 * 4 + 3] += snew * w.w;
    }
  }
  float o0 = b2[(size_t)d * 2], o1 = b2[(size_t)d * 2 + 1];
  #pragma unroll
  for (int h2 = 0; h2 < HNN; h2++){
    float hh = hp[h2] * sigm(hp[h2 + HNN]);
    o0 += hh * w2[((size_t)(h2 * 2)) * DD + d];
    o1 += hh * w2[((size_t)(h2 * 2 + 1)) * DD + d];
  }
  act[(size_t)d * 64 + lane] = o0 * sigm(o1);
}

// ---------------- certainty from stored predictions ----------------
__global__ __launch_bounds__(256) void cert_kernel(float* __restrict__ dout)
{
  int blk = blockIdx.x;
  int b = blk / TT, t = blk % TT;
  int tid = threadIdx.x;
  __shared__ float red[256];
  float vals[4];
  float mx = -1e30f;
  #pragma unroll
  for (int i = 0; i < 4; i++){
    int n = tid + i * 256;
    float v = (n < OUTN) ? dout[((size_t)b * OUTN + n) * TT + t] : -1e30f;
    vals[i] = v; mx = fmaxf(mx, v);
  }
  red[tid] = mx; __syncthreads();
  for (int st = 128; st > 0; st >>= 1){ if (tid < st) red[tid] = fmaxf(red[tid], red[tid + st]); __syncthreads(); }
  mx = red[0]; __syncthreads();
  float z = 0.f, s1 = 0.f;
  #pragma unroll
  for (int i = 0; i < 4; i++){
    int n = tid + i * 256;
    if (n < OUTN){
      float e = expf(vals[i] - mx);
      z += e; s1 += e * (vals[i] - mx);
    }
  }
  red[tid] = z; __syncthreads();
  for (int st = 128; st > 0; st >>= 1){ if (tid < st) red[tid] += red[tid + st]; __syncthreads(); }
  z = red[0]; __syncthreads();
  red[tid] = s1; __syncthreads();
  for (int st = 128; st > 0; st >>= 1){ if (tid < st) red[tid] += red[tid + st]; __syncthreads(); }
  s1 = red[0];
  if (tid == 0){
    float ne = (logf(z) - s1 / z) * (1.f / logf(1000.f));
    dout[CERT_OFF + ((size_t)b * 2 + 0) * TT + t] = ne;
    dout[CERT_OFF + ((size_t)b * 2 + 1) * TT + t] = 1.f - ne;
  }
}

extern "C" void kernel_launch(void* const* d_in, const int* in_sizes, int n_in,
                              void* d_out, int out_size, void* d_ws, size_t ws_size,
                              hipStream_t stream)
{
  const float* x    = (const float*)d_in[0];
  const float* Wkv  = (const float*)d_in[1];
  const float* bkv  = (const float*)d_in[2];
  const float* gkv  = (const float*)d_in[3];
  const float* bkv2 = (const float*)d_in[4];
  const float* Wq   = (const float*)d_in[5];
  const float* bq   = (const float*)d_in[6];
  const float* Wqa  = (const float*)d_in[7];
  const float* bqa  = (const float*)d_in[8];
  const float* Wka  = (const float*)d_in[9];
  const float* bka  = (const float*)d_in[10];
  const float* Wva  = (const float*)d_in[11];
  const float* bva  = (const float*)d_in[12];
  const float* Wo   = (const float*)d_in[13];
  const float* bo   = (const float*)d_in[14];
  const float* Wsyn = (const float*)d_in[15];
  const float* bsyn = (const float*)d_in[16];
  const float* gsyn = (const float*)d_in[17];
  const float* bsn  = (const float*)d_in[18];
  const float* w1   = (const float*)d_in[19];
  const float* b1   = (const float*)d_in[20];
  const float* w2   = (const float*)d_in[21];
  const float* b2   = (const float*)d_in[22];
  const float* sact = (const float*)d_in[23];
  const float* strc = (const float*)d_in[24];
  const float* dcA  = (const float*)d_in[25];
  const float* dcO  = (const float*)d_in[26];
  const float* Wout = (const float*)d_in[27];
  const float* bout = (const float*)d_in[28];
  const int* ial = (const int*)d_in[29];
  const int* iar = (const int*)d_in[30];
  const int* iol = (const int*)d_in[31];
  const int* ior = (const int*)d_in[32];

  char* ws = (char*)d_ws;
  float* khT  = (float*)(ws + 0);          // 25,690,112
  float* vh   = (float*)(ws + 25690112);   // 25,690,112
  // precompute chunk scratch (dead before init_kernel):
  float* B0   = (float*)(ws + 51380224);   // 6,422,528
  float* B1   = (float*)(ws + 57802752);   // 6,422,528
  // step-time region:
  float* tr       = (float*)(ws + 51380224);   // 13,107,200
  float* attnproj = (float*)(ws + 64487424);   // 131,072   [0..511][b]
  float* act      = (float*)(ws + 64618496);   // 524,288   [512..2559][b] (A-contig!)
  float* sA       = (float*)(ws + 65142784);   // 131,072
  float* q2e      = (float*)(ws + 65273856);   // 131,072
  float* ao       = (float*)(ws + 65404928);   // 131,072
  float* glupre   = (float*)(ws + 65536000);   // 524,288
  float* psum     = (float*)(ws + 66060288);   // 65,536
  float* psq      = (float*)(ws + 66125824);   // 65,536
  float* aA       = (float*)(ws + 66191360);   // 131,072
  float* bA       = (float*)(ws + 66322432);   // 131,072
  float* aO       = (float*)(ws + 66453504);   // 131,072
  float* bO       = (float*)(ws + 66584576);   // 131,072
  float* so       = (float*)(ws + 66715648);   // 131,072
  float* Wqqt     = (float*)(ws + 66846720);   // 1,048,576
  float* Wot      = (float*)(ws + 67895296);   // 1,048,576
  float* WoutT    = (float*)(ws + 68943872);   // 2,048,000
  float* bqqb     = (float*)(ws + 70991872);   // 2,048
  float* rA       = (float*)(ws + 70993920);   // 2,048
  float* rO       = (float*)(ws + 70995968);   // 2,048
  float* dout = (float*)d_out;

  // precompute kv -> khT / vh in 4 row-chunks of 3136
  for (int c = 0; c < 4; c++){
    const float* xc = x + (size_t)c * 3136 * EE;
    sgemm<0><<<dim3(49, 8), 256, 0, stream>>>(xc, Wkv, bkv, B0, 3136, EE, EE, 0);
    ln_rows_kernel<<<3136, 256, 0, stream>>>(B0, gkv, bkv2, B1);
    sgemm<3><<<dim3(49, 8), 256, 0, stream>>>(B1, Wka, bka, khT, 3136, EE, EE, c * 3136);
    sgemm<1><<<dim3(49, 8), 256, 0, stream>>>(B1, Wva, bva, vh, 3136, EE, EE, c * 3136);
  }
  // folded query weights; transposed Wo / Wout; rates; state init
  sgemm<2><<<dim3(8, 8), 256, 0, stream>>>(Wq, Wqa, nullptr, Wqqt, EE, EE, EE, 0);
  bqq_kernel<<<1, 512, 0, stream>>>(bq, Wqa, bqa, bqqb);
  transposeMN<<<dim3(16, 16), dim3(32, 8), 0, stream>>>(Wo, Wot, EE, EE);
  transposeMN<<<dim3(32, 16), dim3(32, 8), 0, stream>>>(Wout, WoutT, EE, OUTN);
  prep_decay<<<1, 512, 0, stream>>>(dcA, dcO, rA, rO);
  init_kernel<<<512, 256, 0, stream>>>(sact, strc, iol, ior, act, tr, aA, bA, aO, bO);

  for (int t = 0; t < TT; t++){
    k_sync<<<128, 512, 0, stream>>>(act, aA, bA, aO, bO, sA, so, rA, rO,
                                    ial, iar, iol, ior, dout, t);
    k_gemv2<<<256, 512, 0, stream>>>(sA, Wqqt, bqqb, so, WoutT, bout, q2e, dout, t);
    k_attn<<<256, 512, 0, stream>>>(q2e, khT, vh, ao);
    k_wo<<<256, 512, 0, stream>>>(ao, Wot, bo, attnproj);
    k_syn<<<256, 512, 0, stream>>>(attnproj, Wsyn, bsyn, glupre, psum, psq);
    k_nlm<<<256, 512, 0, stream>>>(glupre, psum, psq, gsyn, bsn, w1, b1, w2, b2,
                                   tr, act, t);
  }
  // final sO(49) + out-GEMV(49)
  k_sync<<<128, 512, 0, stream>>>(act, aA, bA, aO, bO, sA, so, rA, rO,
                                  ial, iar, iol, ior, dout, TT);
  k_gemv2<<<256, 512, 0, stream>>>(sA, Wqqt, bqqb, so, WoutT, bout, q2e, dout, TT);
  cert_kernel<<<BB * TT, 256, 0, stream>>>(dout);
}